// Round 7
// baseline (469.272 us; speedup 1.0000x reference)
//
#include <hip/hip_runtime.h>
#include <hip/hip_bf16.h>
#include <math.h>

// Problem constants
#define S_TOK   8192
#define DIM     1280
#define NHEAD   16
#define HDIM    80
#define NSEG    8
#define SEGLEN  1024
#define QKV_LD  3840
#define DPAD    96      // head_dim padded to 6*16 for 32x32x16 MFMA k-steps

typedef __attribute__((ext_vector_type(8)))  short bf16x8;   // 8 bf16 = 4 VGPR
typedef __attribute__((ext_vector_type(4)))  float f32x4;
typedef __attribute__((ext_vector_type(16))) float f32x16;   // 32x32 MFMA acc

__device__ __forceinline__ short f2b(float x) {
  __hip_bfloat16 h = __float2bfloat16(x);
  return *reinterpret_cast<short*>(&h);
}
__device__ __forceinline__ float b2f(short x) {
  __hip_bfloat16 h;
  *reinterpret_cast<short*>(&h) = x;
  return __bfloat162float(h);
}

__device__ __forceinline__ void gl_lds16(const void* g, void* l) {
  __builtin_amdgcn_global_load_lds(
      (const __attribute__((address_space(1))) unsigned int*)g,
      (__attribute__((address_space(3))) unsigned int*)l, 16, 0, 0);
}

// ---------------------------------------------------------------------------
// f32 -> bf16 cast (vectorized)
// ---------------------------------------------------------------------------
__global__ __launch_bounds__(256) void cast_f32_bf16(
    const float* __restrict__ in, short* __restrict__ out, int n4)
{
  const int i = blockIdx.x * 256 + threadIdx.x;
  if (i >= n4) return;
  const float4 v = ((const float4*)in)[i];
  short4 o;
  o.x = f2b(v.x); o.y = f2b(v.y); o.z = f2b(v.z); o.w = f2b(v.w);
  ((short4*)out)[i] = o;
}

// ---------------------------------------------------------------------------
// bf16 MFMA NT-GEMM: C[M,N] = A[M,K] @ B[N,K]^T + bias
// 128x128 tile, BK=64 (32 MFMA per barrier-pair), 4 waves (2x2).
// LDS [128][64] shorts: 128B row stride would be 16-way bank conflicted on
// frag reads, so slots are XOR-swizzled (slot^(row&7)) BOTH sides (rule #21):
// linear gl_lds dest + inverse-permuted global source + same XOR on read.
// ---------------------------------------------------------------------------
template<bool OUT_BF16>
__global__ __launch_bounds__(256) void gemm_mfma_nt(
    const short* __restrict__ A, const short* __restrict__ B,
    const float* __restrict__ bias, void* __restrict__ Cout,
    int M, int N, int K)
{
  __shared__ short As[128 * 64];
  __shared__ short Bs[128 * 64];
  const int t = threadIdx.x;
  const int wave = t >> 6, lane = t & 63;
  const int q = lane >> 4, r = lane & 15;
  const int bm = blockIdx.y * 128, bn = blockIdx.x * 128;
  const int wr = (wave >> 1) * 64, wc = (wave & 1) * 64;

  f32x4 acc[4][4];
#pragma unroll
  for (int i = 0; i < 4; ++i)
#pragma unroll
    for (int j = 0; j < 4; ++j) acc[i][j] = (f32x4)(0.f);

  for (int k0 = 0; k0 < K; k0 += 64) {
    __syncthreads();
    // 1024 chunks of 16B per matrix; chunk c -> row c>>3, slot c&7.
    // source column slot^(row&7) so that LDS holds the swizzled layout.
#pragma unroll
    for (int i = 0; i < 4; ++i) {
      const int c = i * 256 + t;
      const int row = c >> 3, slot = c & 7;
      const int soff = (slot ^ (row & 7)) * 8;
      gl_lds16(A + (size_t)(bm + row) * K + k0 + soff, As + c * 8);
      gl_lds16(B + (size_t)(bn + row) * K + k0 + soff, Bs + c * 8);
    }
    __syncthreads();

#pragma unroll
    for (int kk = 0; kk < 2; ++kk) {
      bf16x8 af[4], bg[4];
#pragma unroll
      for (int mt = 0; mt < 4; ++mt) {
        const int row = wr + mt * 16 + r;
        af[mt] = *(const bf16x8*)&As[row * 64 + ((kk * 4 + q) ^ (row & 7)) * 8];
      }
#pragma unroll
      for (int nt = 0; nt < 4; ++nt) {
        const int row = wc + nt * 16 + r;
        bg[nt] = *(const bf16x8*)&Bs[row * 64 + ((kk * 4 + q) ^ (row & 7)) * 8];
      }
#pragma unroll
      for (int mt = 0; mt < 4; ++mt)
#pragma unroll
        for (int nt = 0; nt < 4; ++nt)
          acc[mt][nt] = __builtin_amdgcn_mfma_f32_16x16x32_bf16(
              af[mt], bg[nt], acc[mt][nt], 0, 0, 0);
    }
  }

#pragma unroll
  for (int mt = 0; mt < 4; ++mt)
#pragma unroll
    for (int nt = 0; nt < 4; ++nt)
#pragma unroll
      for (int reg = 0; reg < 4; ++reg) {
        const int mrow = bm + wr + mt * 16 + q * 4 + reg;
        const int ncol = bn + wc + nt * 16 + r;
        const float v = acc[mt][nt][reg] + bias[ncol];
        if (OUT_BF16)
          ((short*)Cout)[(size_t)mrow * N + ncol] = f2b(v);
        else
          ((float*)Cout)[(size_t)mrow * N + ncol] = v;
      }
}

// ---------------------------------------------------------------------------
// RoPE on bf16 qkv -> padded Q (pre-scaled by D^-1/2 * log2(e): softmax runs
// in exp2 domain) and K, [S][NHEAD][96] bf16, zeros in [80,96).
// ---------------------------------------------------------------------------
__global__ __launch_bounds__(256) void rope_cast(
    const short* __restrict__ qkvb, const float* __restrict__ rot,
    short* __restrict__ Qb, short* __restrict__ Kb)
{
  const int idx = blockIdx.x * 256 + threadIdx.x;   // S*16*48
  const int j = idx % 48;
  const int h = (idx / 48) % NHEAD;
  const int s = idx / (48 * NHEAD);
  short* qo = Qb + ((size_t)s * NHEAD + h) * DPAD;
  short* ko = Kb + ((size_t)s * NHEAD + h) * DPAD;
  if (j < 40) {
    const float f = rot[s * 40 + j];
    const float c = cosf(f), sn = sinf(f);
    const short* qi = qkvb + (size_t)s * QKV_LD + h * HDIM;
    const short* ki = qi + DIM;
    const float scale = 0.11180339887498949f * 1.4426950408889634f;
    const float q0 = b2f(qi[j]), q1 = b2f(qi[j + 40]);
    qo[j]      = f2b((q0 * c - q1 * sn) * scale);
    qo[j + 40] = f2b((q1 * c + q0 * sn) * scale);
    const float k0 = b2f(ki[j]), k1 = b2f(ki[j + 40]);
    ko[j]      = f2b(k0 * c - k1 * sn);
    ko[j + 40] = f2b(k1 * c + k0 * sn);
  } else {
    const int z = 80 + (j - 40);    // zero-pad [80,96)
    qo[z] = 0; qo[z + 8] = 0;
    ko[z] = 0; ko[z + 8] = 0;
  }
}

// ---------------------------------------------------------------------------
// V transpose in global: qkv_b V-section -> Vt[seg][head][d][1024] bf16.
// ---------------------------------------------------------------------------
__global__ __launch_bounds__(256) void v_transpose(
    const short* __restrict__ qkvb, short* __restrict__ Vt)
{
  const int tid = blockIdx.x * 256 + threadIdx.x;   // 160 * 8192
  const int c   = tid >> 13;         // 0..159 : chunk col (head*10 + grp)
  const int kv  = tid & 8191;
  const int head = c / 10;
  const int d0   = (c % 10) * 8;
  const int seg  = kv >> 10;
  const bf16x8 v = *(const bf16x8*)(qkvb + (size_t)kv * QKV_LD + 2 * DIM +
                                    head * HDIM + d0);
  short* ob = Vt + ((size_t)(seg * NHEAD + head) * HDIM + d0) * SEGLEN + (kv & 1023);
#pragma unroll
  for (int j = 0; j < 8; ++j)
    ob[(size_t)j * SEGLEN] = v[j];
}

// ---------------------------------------------------------------------------
// bf16 flash attention, swapped 32x32x16 MFMA, double-buffered K/V LDS.
// grid (4, 16, 8); 4 waves x 64 q-rows (ABM=256); KV tiles of 64.
// ONE barrier per tile: at iter t (post-barrier) stage buf[(t+1)&1] while
// computing buf[t&1]; barrier proves buf[t] written and buf[t+1] free.
// Softmax in-lane (P^T layout) + one shfl_xor(32); P packed in-register.
// ---------------------------------------------------------------------------
#define LQK 104   // K LDS row stride (halves)
#define LVT 72    // V^T row stride
#define NTILE 16  // SEGLEN/64

__global__ __launch_bounds__(256, 2) void attn_mfma(
    const short* __restrict__ Qb, const short* __restrict__ Kb,
    const short* __restrict__ Vtg, short* __restrict__ ctxb)
{
  __shared__ short Ks[2][64 * LQK];
  __shared__ short Vs[2][96 * LVT];    // rows 80..95 stay zero

  const int t = threadIdx.x;
  const int wave = t >> 6, lane = t & 63;
  const int c = lane & 31, hi = lane >> 5;
  const int seg = blockIdx.z, head = blockIdx.y;
  const int m0 = blockIdx.x * 256;
  const size_t srow0 = (size_t)seg * SEGLEN;
  const size_t vbase = (size_t)(seg * NHEAD + head) * HDIM * SEGLEN;

  // zero both V^T pad-row regions once
  for (int i = t; i < 16 * LVT / 2; i += 256) {
    ((int*)(Vs[0] + 80 * LVT))[i] = 0;
    ((int*)(Vs[1] + 80 * LVT))[i] = 0;
  }

  // Q B-frags in registers
  bf16x8 qf[2][6];
#pragma unroll
  for (int u = 0; u < 2; ++u)
#pragma unroll
    for (int ks = 0; ks < 6; ++ks)
      qf[u][ks] = *(const bf16x8*)(
          Qb + ((srow0 + m0 + wave * 64 + u * 32 + c) * NHEAD + head) * DPAD +
          ks * 16 + hi * 8);

  f32x16 o[3][2];
#pragma unroll
  for (int d = 0; d < 3; ++d)
#pragma unroll
    for (int u = 0; u < 2; ++u) o[d][u] = (f32x16)(0.f);
  float m_[2] = {-1e30f, -1e30f}, l_[2] = {0.f, 0.f};

  const int kc_row[3] = {(0 * 256 + t) / 12, (1 * 256 + t) / 12, (2 * 256 + t) / 12};
  const int kc_off[3] = {((0 * 256 + t) % 12) * 8, ((1 * 256 + t) % 12) * 8,
                         ((2 * 256 + t) % 12) * 8};
  bf16x8 kreg[3], vreg[3];

#define LOAD_K(n0)                                                             \
  {                                                                            \
    _Pragma("unroll")                                                          \
    for (int i = 0; i < 3; ++i)                                                \
      kreg[i] = *(const bf16x8*)(                                              \
          Kb + ((srow0 + (n0) + kc_row[i]) * NHEAD + head) * DPAD + kc_off[i]);\
  }
#define LOAD_V(n0)                                                             \
  {                                                                            \
    _Pragma("unroll")                                                          \
    for (int i = 0; i < 3; ++i) {                                              \
      const int cc = i * 256 + t;                                              \
      if (cc < 640)                                                            \
        vreg[i] = *(const bf16x8*)(Vtg + vbase + (size_t)(cc >> 3) * SEGLEN +  \
                                   (n0) + (cc & 7) * 8);                       \
    }                                                                          \
  }
#define STORE_KV(buf)                                                          \
  {                                                                            \
    _Pragma("unroll")                                                          \
    for (int i = 0; i < 3; ++i)                                                \
      *(bf16x8*)&Ks[buf][kc_row[i] * LQK + kc_off[i]] = kreg[i];               \
    _Pragma("unroll")                                                          \
    for (int i = 0; i < 3; ++i) {                                              \
      const int cc = i * 256 + t;                                              \
      if (cc < 640)                                                            \
        *(bf16x8*)&Vs[buf][(cc >> 3) * LVT + (cc & 7) * 8] = vreg[i];          \
    }                                                                          \
  }

  // prologue: stage tile 0 into buf0, prefetch tile 1 into regs
  LOAD_K(0)
  LOAD_V(0)
  STORE_KV(0)
  LOAD_K(64)
  LOAD_V(64)

  for (int tile = 0; tile < NTILE; ++tile) {
    __syncthreads();   // buf[tile&1] complete; buf[tile+1&1] free
    const int cur = tile & 1;
    if (tile + 1 < NTILE) STORE_KV(cur ^ 1)            // overlaps compute
    if (tile + 2 < NTILE) { LOAD_K((tile + 2) * 64) LOAD_V((tile + 2) * 64) }
    const short* ksc = Ks[cur];
    const short* vsc = Vs[cur];

    // QK^T swapped: s[tt][u] = K-tile(tt) x Q-tile(u), D = P^T[kv][q]
    f32x16 s[2][2];
#pragma unroll
    for (int tt = 0; tt < 2; ++tt)
#pragma unroll
      for (int u = 0; u < 2; ++u) s[tt][u] = (f32x16)(0.f);
    __builtin_amdgcn_s_setprio(1);
#pragma unroll
    for (int tt = 0; tt < 2; ++tt)
#pragma unroll
      for (int ks = 0; ks < 6; ++ks) {
        const bf16x8 kf =
            *(const bf16x8*)&ksc[(tt * 32 + c) * LQK + ks * 16 + hi * 8];
        s[tt][0] = __builtin_amdgcn_mfma_f32_32x32x16_bf16(kf, qf[0][ks], s[tt][0], 0, 0, 0);
        s[tt][1] = __builtin_amdgcn_mfma_f32_32x32x16_bf16(kf, qf[1][ks], s[tt][1], 0, 0, 0);
      }
    __builtin_amdgcn_s_setprio(0);

    // softmax (exp2 domain) + in-register P pack, per q-tile u
    bf16x8 pf[2][4];
#pragma unroll
    for (int u = 0; u < 2; ++u) {
      float a0 = -1e30f, a1 = -1e30f, a2 = -1e30f, a3 = -1e30f;
#pragma unroll
      for (int tt = 0; tt < 2; ++tt)
#pragma unroll
        for (int i = 0; i < 16; i += 4) {
          a0 = fmaxf(a0, s[tt][u][i]);
          a1 = fmaxf(a1, s[tt][u][i + 1]);
          a2 = fmaxf(a2, s[tt][u][i + 2]);
          a3 = fmaxf(a3, s[tt][u][i + 3]);
        }
      float mx = fmaxf(fmaxf(a0, a1), fmaxf(a2, a3));
      mx = fmaxf(mx, __shfl_xor(mx, 32));
      if (!__all(mx <= m_[u])) {          // skip rescale when max unchanged
        const float mn = fmaxf(m_[u], mx);
        const float corr = exp2f(m_[u] - mn);
        m_[u] = mn;
        l_[u] *= corr;
#pragma unroll
        for (int d = 0; d < 3; ++d)
#pragma unroll
          for (int i = 0; i < 16; ++i) o[d][u][i] *= corr;
      }
      float s0 = 0.f, s1 = 0.f, s2 = 0.f, s3 = 0.f;
#pragma unroll
      for (int tt = 0; tt < 2; ++tt)
#pragma unroll
        for (int i = 0; i < 16; i += 4) {
          const float e0 = exp2f(s[tt][u][i] - m_[u]);
          const float e1 = exp2f(s[tt][u][i + 1] - m_[u]);
          const float e2 = exp2f(s[tt][u][i + 2] - m_[u]);
          const float e3 = exp2f(s[tt][u][i + 3] - m_[u]);
          s[tt][u][i] = e0; s[tt][u][i + 1] = e1;
          s[tt][u][i + 2] = e2; s[tt][u][i + 3] = e3;
          s0 += e0; s1 += e1; s2 += e2; s3 += e3;
        }
      float sum = (s0 + s1) + (s2 + s3);
      sum += __shfl_xor(sum, 32);
      l_[u] += sum;

      // pack P^T to bf16 dwords: d8[tt][i] = {p[2i] lo, p[2i+1] hi}
      unsigned d8[2][8];
#pragma unroll
      for (int tt = 0; tt < 2; ++tt)
#pragma unroll
        for (int i = 0; i < 8; ++i)
          d8[tt][i] = ((unsigned)(unsigned short)f2b(s[tt][u][2 * i + 1]) << 16) |
                      (unsigned short)f2b(s[tt][u][2 * i]);
      // half-wave exchange: send what the partner needs, receive ours
      unsigned rcv[2][4];
#pragma unroll
      for (int tt = 0; tt < 2; ++tt) {
        const unsigned sd0 = hi ? d8[tt][0] : d8[tt][2];
        const unsigned sd1 = hi ? d8[tt][1] : d8[tt][3];
        const unsigned sd2 = hi ? d8[tt][4] : d8[tt][6];
        const unsigned sd3 = hi ? d8[tt][5] : d8[tt][7];
        rcv[tt][0] = __shfl_xor((int)sd0, 32);
        rcv[tt][1] = __shfl_xor((int)sd1, 32);
        rcv[tt][2] = __shfl_xor((int)sd2, 32);
        rcv[tt][3] = __shfl_xor((int)sd3, 32);
      }
      // assemble B-frags: kv = ks*16 + hi*8 + j (tt = ks>>1, k2 = ks&1)
#pragma unroll
      for (int ks = 0; ks < 4; ++ks) {
        const int tt = ks >> 1, k2 = ks & 1;
        int4 pw;
        pw.x = hi ? (int)rcv[tt][2 * k2]     : (int)d8[tt][4 * k2];
        pw.y = hi ? (int)rcv[tt][2 * k2 + 1] : (int)d8[tt][4 * k2 + 1];
        pw.z = hi ? (int)d8[tt][4 * k2 + 2]  : (int)rcv[tt][2 * k2];
        pw.w = hi ? (int)d8[tt][4 * k2 + 3]  : (int)rcv[tt][2 * k2 + 1];
        pf[u][ks] = *reinterpret_cast<bf16x8*>(&pw);
      }
    }

    // PV: O^T[d][q] += V^T * P^T
    __builtin_amdgcn_s_setprio(1);
#pragma unroll
    for (int dt = 0; dt < 3; ++dt)
#pragma unroll
      for (int ks = 0; ks < 4; ++ks) {
        const bf16x8 vf =
            *(const bf16x8*)&vsc[(dt * 32 + c) * LVT + ks * 16 + hi * 8];
        o[dt][0] = __builtin_amdgcn_mfma_f32_32x32x16_bf16(vf, pf[0][ks], o[dt][0], 0, 0, 0);
        o[dt][1] = __builtin_amdgcn_mfma_f32_32x32x16_bf16(vf, pf[1][ks], o[dt][1], 0, 0, 0);
      }
    __builtin_amdgcn_s_setprio(0);
  }

  // epilogue: O^T -> ctx[q][head*80+d], 4 consecutive d per (g,hi) group
#pragma unroll
  for (int u = 0; u < 2; ++u) {
    const float inv = 1.f / l_[u];
    const size_t row = srow0 + m0 + wave * 64 + u * 32 + c;
#pragma unroll
    for (int dt = 0; dt < 3; ++dt)
#pragma unroll
      for (int g = 0; g < 4; ++g) {
        const int d0 = dt * 32 + 8 * g + 4 * hi;
        if (d0 < HDIM) {
          short4 v4;
          v4.x = f2b(o[dt][u][4 * g + 0] * inv);
          v4.y = f2b(o[dt][u][4 * g + 1] * inv);
          v4.z = f2b(o[dt][u][4 * g + 2] * inv);
          v4.w = f2b(o[dt][u][4 * g + 3] * inv);
          *(short4*)&ctxb[row * DIM + head * HDIM + d0] = v4;
        }
      }
  }
}

// ---------------------------------------------------------------------------
extern "C" void kernel_launch(void* const* d_in, const int* in_sizes, int n_in,
                              void* d_out, int out_size, void* d_ws, size_t ws_size,
                              hipStream_t stream)
{
  const float* hs    = (const float*)d_in[0];
  const float* rot   = (const float*)d_in[1];
  const float* wqkv  = (const float*)d_in[2];
  const float* bqkv  = (const float*)d_in[3];
  const float* wproj = (const float*)d_in[4];
  const float* bproj = (const float*)d_in[5];
  float* out = (float*)d_out;

  char* w = (char*)d_ws;
  short* hs_b    = (short*)w;  w += (size_t)S_TOK * DIM * 2;      // 21 MB
  short* wqkv_b  = (short*)w;  w += (size_t)QKV_LD * DIM * 2;
  short* wproj_b = (short*)w;  w += (size_t)DIM * DIM * 2;
  short* qkv_b   = (short*)w;  w += (size_t)S_TOK * QKV_LD * 2;
  short* Qb      = (short*)w;  w += (size_t)S_TOK * NHEAD * DPAD * 2;
  short* Kb      = (short*)w;  w += (size_t)S_TOK * NHEAD * DPAD * 2;
  short* ctx_b   = (short*)w;  w += (size_t)S_TOK * DIM * 2;
  short* Vt_g    = hs_b;   // reuse: hs_b dead after QKV GEMM (21 MB exact)

  dim3 blk(256);

  cast_f32_bf16<<<dim3(S_TOK * DIM / 4 / 256), blk, 0, stream>>>(hs, hs_b, S_TOK * DIM / 4);
  cast_f32_bf16<<<dim3(QKV_LD * DIM / 4 / 256), blk, 0, stream>>>(wqkv, wqkv_b, QKV_LD * DIM / 4);
  cast_f32_bf16<<<dim3(DIM * DIM / 4 / 256), blk, 0, stream>>>(wproj, wproj_b, DIM * DIM / 4);

  gemm_mfma_nt<true><<<dim3(QKV_LD / 128, S_TOK / 128), blk, 0, stream>>>(
      hs_b, wqkv_b, bqkv, qkv_b, S_TOK, QKV_LD, DIM);

  rope_cast<<<dim3(S_TOK * NHEAD * 48 / 256), blk, 0, stream>>>(qkv_b, rot, Qb, Kb);

  v_transpose<<<dim3(160 * S_TOK / 256), blk, 0, stream>>>(qkv_b, Vt_g);

  attn_mfma<<<dim3(SEGLEN / 256, NHEAD, NSEG), blk, 0, stream>>>(Qb, Kb, Vt_g, ctx_b);

  gemm_mfma_nt<false><<<dim3(DIM / 128, S_TOK / 128), blk, 0, stream>>>(
      ctx_b, wproj_b, bproj, out, S_TOK, DIM, DIM);
}